// Round 15
// baseline (554.348 us; speedup 1.0000x reference)
//
#include <hip/hip_runtime.h>
#include <hip/hip_bf16.h>

// SymbolicGNN, CSR two-phase, v15.
// v14 post-mortem: k_msg == v12 fixed point (3rd confirmation); pool/final fusion
// neutral-to-negative -> reverted to v12's separate k_pool/k_final. New lever:
// fuse msg(L0)+h2b+msg(L1) into ONE resident-grid kernel (grid 1024 == exact
// residency, proven at 4 blocks/CU since v8) with manual sense-counter grid
// barriers + agent fences. Deletes two kernel-end drains + one launch. Runtime
// occupancy query gates the fused path: if the compiler's allocation drops
// blocks/CU below 4, fall back to the v12 three-launch path (no deadlock risk).

#define N_NODES 100000
#define NV_ELEMS (N_NODES * 64)
#define N_EDGES 1000000
#define EV_ELEMS (131075 * 64)   // VOCAB * ES
#define ES 64
#define TILE 32
#define NTILES (N_EDGES / TILE)
#define MSG_GRID 1024            // == residency capacity: 4 blocks/CU x 256 CU
#define SCAN_B 1024
#define SCAN_NB ((N_NODES + SCAN_B - 1) / SCAN_B)   // 98

typedef __bf16 bf16x8 __attribute__((ext_vector_type(8)));
typedef __bf16 bf16x4 __attribute__((ext_vector_type(4)));
typedef float f32x4 __attribute__((ext_vector_type(4)));

__device__ __forceinline__ f32x4 mfma_16x16x32(bf16x8 a, bf16x8 b, f32x4 c) {
    return __builtin_amdgcn_mfma_f32_16x16x32_bf16(a, b, c, 0, 0, 0);
}

// LDS-only barrier: cross-thread deps in the msg body are all LDS; global loads
// (gather prefetch) and atomics stay in flight across it.
#define BAR() asm volatile("s_waitcnt lgkmcnt(0)\n\ts_barrier" ::: "memory")

// tanh-GELU via sigmoid identity: v * rcp(1 + exp2(-(2.30227911 v + 0.10294538 v^3))).
// Overflow-safe both directions. 2 transcendental + ~5 ALU per element.
__device__ __forceinline__ f32x4 gelu4(f32x4 v) {
    f32x4 z = v * (v * v * -0.10294538f + -2.30227911f);
    f32x4 t;
#pragma unroll
    for (int i = 0; i < 4; ++i) t[i] = __builtin_amdgcn_exp2f(z[i]);
    f32x4 o = t + 1.0f;
    f32x4 r;
#pragma unroll
    for (int i = 0; i < 4; ++i) r[i] = __builtin_amdgcn_rcpf(o[i]);
    return v * r;
}

// grid-wide barrier: requires all gridDim.x blocks resident (gated by host-side
// occupancy query). Release fence -> arrive -> spin acquire -> block-wide fence.
__device__ __forceinline__ void grid_barrier(int* ctr) {
    __syncthreads();
    __threadfence();   // release: publish this block's writes device-wide
    if (threadIdx.x == 0) {
        __hip_atomic_fetch_add(ctr, 1, __ATOMIC_ACQ_REL, __HIP_MEMORY_SCOPE_AGENT);
        while (__hip_atomic_load(ctr, __ATOMIC_ACQUIRE, __HIP_MEMORY_SCOPE_AGENT)
               < (int)gridDim.x)
            __builtin_amdgcn_s_sleep(8);
    }
    __syncthreads();
    __threadfence();   // acquire: invalidate stale cached lines before reading
}

__global__ void k_init(const float* __restrict__ sym, const float* __restrict__ eemb,
                       const float* __restrict__ w1, const float* __restrict__ w2,
                       const int* __restrict__ obj,
                       float* __restrict__ A, __bf16* __restrict__ hb,
                       __bf16* __restrict__ ebb,
                       __bf16* __restrict__ w1b, __bf16* __restrict__ w2b,
                       float* __restrict__ pooled, int* __restrict__ cnt) {
    const int gid = blockIdx.x * blockDim.x + threadIdx.x;
    const int gstride = gridDim.x * blockDim.x;
    const int nv4 = NV_ELEMS / 4;
    const float4* s4 = (const float4*)sym;
    float4* a4 = (float4*)A;
    for (int i = gid; i < nv4; i += gstride) {
        float4 v = s4[i];
        a4[i] = v;
        bf16x4 p;
        p[0] = (__bf16)v.x; p[1] = (__bf16)v.y; p[2] = (__bf16)v.z; p[3] = (__bf16)v.w;
        *(bf16x4*)(hb + (size_t)i * 4) = p;
    }
    const int ev4 = EV_ELEMS / 4;
    const float4* e4 = (const float4*)eemb;
    for (int i = gid; i < ev4; i += gstride) {
        float4 v = e4[i];
        bf16x4 p;
        p[0] = (__bf16)v.x; p[1] = (__bf16)v.y; p[2] = (__bf16)v.z; p[3] = (__bf16)v.w;
        *(bf16x4*)(ebb + (size_t)i * 4) = p;
    }
    // W1 -> fragment order: [layer][kt(6)][lg(4)][col(128)][i(8)], elem k = kt*32+lg*8+i
    for (int d = gid; d < 2 * 24576; d += gstride) {
        int layer = d / 24576, r = d - layer * 24576;
        int kt = r >> 12, lg = (r >> 10) & 3, col = (r >> 3) & 127, i = r & 7;
        w1b[d] = (__bf16)w1[layer * 24576 + (kt * 32 + lg * 8 + i) * 128 + col];
    }
    // W2 -> [layer][kt(4)][lg(4)][col(64)][i(8)]
    for (int d = gid; d < 2 * 8192; d += gstride) {
        int layer = d >> 13, r = d & 8191;
        int kt = r >> 11, lg = (r >> 9) & 3, col = (r >> 3) & 63, i = r & 7;
        w2b[d] = (__bf16)w2[layer * 8192 + (kt * 32 + lg * 8 + i) * 64 + col];
    }
    // histogram of obj (cnt pre-zeroed by hipMemsetAsync before this launch)
    for (int i = gid; i < N_EDGES; i += gstride) atomicAdd(&cnt[obj[i]], 1);
    if (gid < ES) pooled[gid] = 0.0f;
}

__global__ void k_h2b(const float* __restrict__ A, __bf16* __restrict__ hb) {
    const int nv4 = NV_ELEMS / 4;
    const float4* a4 = (const float4*)A;
    for (int i = blockIdx.x * blockDim.x + threadIdx.x; i < nv4;
         i += gridDim.x * blockDim.x) {
        float4 v = a4[i];
        bf16x4 p;
        p[0] = (__bf16)v.x; p[1] = (__bf16)v.y; p[2] = (__bf16)v.z; p[3] = (__bf16)v.w;
        *(bf16x4*)(hb + (size_t)i * 4) = p;
    }
}

__global__ __launch_bounds__(1024) void k_scanA(const int* __restrict__ cnt,
                                                int* __restrict__ off,
                                                int* __restrict__ bsum) {
    __shared__ int sp[SCAN_B];
    const int t = threadIdx.x;
    const int g = blockIdx.x * SCAN_B + t;
    int v = (g < N_NODES) ? cnt[g] : 0;
    sp[t] = v;
    __syncthreads();
#pragma unroll
    for (int d = 1; d < SCAN_B; d <<= 1) {
        int x = (t >= d) ? sp[t - d] : 0;
        __syncthreads();
        sp[t] += x;
        __syncthreads();
    }
    if (g < N_NODES) off[g] = sp[t] - v;
    if (t == SCAN_B - 1) bsum[blockIdx.x] = sp[t];
}

// fused B+C: each block derives its own prefix of bsum (<=97 independent L2 loads,
// pipelined), then applies it.
__global__ __launch_bounds__(1024) void k_scanC(int* __restrict__ off,
                                                const int* __restrict__ bsum,
                                                int* __restrict__ cur) {
    __shared__ int sboff;
    if (threadIdx.x == 0) {
        int run = 0;
        for (int b = 0; b < (int)blockIdx.x; ++b) run += bsum[b];
        sboff = run;
    }
    __syncthreads();
    const int g = blockIdx.x * SCAN_B + threadIdx.x;
    if (g < N_NODES) {
        int o = off[g] + sboff;
        off[g] = o;
        cur[g] = o;
    }
    if (g == 0) off[N_NODES] = N_EDGES;
}

// 4 edges/thread: 3 int4 index loads instead of 12 scalar loads
__global__ void k_fill(const int* __restrict__ subj, const int* __restrict__ pred,
                       const int* __restrict__ obj, int* __restrict__ cur,
                       int4* __restrict__ eT) {
    int e0 = (blockIdx.x * blockDim.x + threadIdx.x) * 4;
    if (e0 >= N_EDGES) return;   // N_EDGES % 4 == 0 -> full int4 in-bounds
    int4 s4 = *(const int4*)(subj + e0);
    int4 p4 = *(const int4*)(pred + e0);
    int4 o4 = *(const int4*)(obj + e0);
    int pos;
    pos = atomicAdd(&cur[o4.x], 1); eT[pos] = make_int4(s4.x, p4.x, o4.x, 0);
    pos = atomicAdd(&cur[o4.y], 1); eT[pos] = make_int4(s4.y, p4.y, o4.y, 0);
    pos = atomicAdd(&cur[o4.z], 1); eT[pos] = make_int4(s4.z, p4.z, o4.z, 0);
    pos = atomicAdd(&cur[o4.w], 1); eT[pos] = make_int4(s4.w, p4.w, o4.w, 0);
}

// ---------------- msg body (v12, verbatim semantics), shared-memory passed in ----------
struct SmemT {
    __bf16 sX[TILE][200];    // 12.8 KB
    __bf16 sHm[TILE][136];   // 8.7 KB
    float  sMsg[TILE][68];   // 8.7 KB
    int    sO2[2][TILE];     // double-buffered obj ids
};

__device__ __forceinline__ void msg_layer(
    SmemT& sm, const int4* __restrict__ eT,
    const __bf16* __restrict__ hb, const __bf16* __restrict__ ebb,
    float* __restrict__ A,
    const __bf16* __restrict__ w1b, const float* __restrict__ b1,
    const __bf16* __restrict__ w2b, const float* __restrict__ b2) {
    const int tid = threadIdx.x;
    const int w   = tid >> 6;
    const int l   = tid & 63;
    const int lg  = l >> 4;
    const int lc  = l & 15;
    const int r   = tid >> 3;
    const int c8  = tid & 7;

    // ---- weight fragments: one 16B load each, PINNED so compiler can't remat ----
    const __bf16* w1f = w1b + (size_t)(lg * 1024 + (w * 32 + lc) * 8);
    const __bf16* w2f = w2b + (size_t)(lg * 512 + (w * 16 + lc) * 8);
    bf16x8 wb1[6][2];
#pragma unroll
    for (int kt = 0; kt < 6; ++kt)
#pragma unroll
        for (int nt = 0; nt < 2; ++nt) {
            wb1[kt][nt] = *(const bf16x8*)(w1f + kt * 4096 + nt * 128);
            asm volatile("" : "+v"(wb1[kt][nt]));
        }
    bf16x8 wb2[4];
#pragma unroll
    for (int kt = 0; kt < 4; ++kt) {
        wb2[kt] = *(const bf16x8*)(w2f + kt * 2048);
        asm volatile("" : "+v"(wb2[kt]));
    }

    f32x4 b1q[2];
    b1q[0] = *(const f32x4*)(b1 + w * 32 + lg * 4);
    b1q[1] = *(const f32x4*)(b1 + w * 32 + 16 + lg * 4);
    f32x4 b2q = *(const f32x4*)(b2 + w * 16 + lg * 4);

    // XCD-chunked contiguous tile range (grid == residency capacity)
    const int chunk = ((blockIdx.x & 7) << 7) + (blockIdx.x >> 3);
    int       tile  = (int)(((long long)chunk * NTILES) >> 10);
    const int tend  = (int)(((long long)(chunk + 1) * NTILES) >> 10);
    if (tile < tend) {   // if-guard (not return): fused kernel must reach grid barrier
        int j0 = tile * TILE;
        int pp = 0;

        int4 ecur = eT[j0 + r];
        const int jn1 = (tile + 1 < tend) ? (tile + 1) * TILE : j0;
        int4 enxt = eT[jn1 + r];
        bf16x8 rb0 = *(const bf16x8*)(hb  + (size_t)ecur.x * ES + c8 * 8);
        bf16x8 rb1 = *(const bf16x8*)(ebb + (size_t)ecur.y * ES + c8 * 8);
        bf16x8 rb2 = *(const bf16x8*)(hb  + (size_t)ecur.z * ES + c8 * 8);

        for (; tile < tend; ++tile) {
            const int jf = (tile + 2 < tend) ? (tile + 2) * TILE : j0;

            *(bf16x8*)&sm.sX[r][      c8 * 8] = rb0;
            *(bf16x8*)&sm.sX[r][ 64 + c8 * 8] = rb1;
            *(bf16x8*)&sm.sX[r][128 + c8 * 8] = rb2;
            if (c8 == 0) sm.sO2[pp][r] = ecur.z;
            int4 efut = eT[jf + r];
            BAR();  // bar1: sX, sO2 ready

            rb0 = *(const bf16x8*)(hb  + (size_t)enxt.x * ES + c8 * 8);
            rb1 = *(const bf16x8*)(ebb + (size_t)enxt.y * ES + c8 * 8);
            rb2 = *(const bf16x8*)(hb  + (size_t)enxt.z * ES + c8 * 8);

            f32x4 acc1[2][2];
#pragma unroll
            for (int nt = 0; nt < 2; ++nt)
#pragma unroll
                for (int mt = 0; mt < 2; ++mt) acc1[nt][mt] = (f32x4){0.f, 0.f, 0.f, 0.f};
#pragma unroll
            for (int kt = 0; kt < 6; ++kt) {
                bf16x8 x0 = *(const bf16x8*)&sm.sX[lc][kt * 32 + lg * 8];
                bf16x8 x1 = *(const bf16x8*)&sm.sX[16 + lc][kt * 32 + lg * 8];
                acc1[0][0] = mfma_16x16x32(wb1[kt][0], x0, acc1[0][0]);
                acc1[0][1] = mfma_16x16x32(wb1[kt][0], x1, acc1[0][1]);
                acc1[1][0] = mfma_16x16x32(wb1[kt][1], x0, acc1[1][0]);
                acc1[1][1] = mfma_16x16x32(wb1[kt][1], x1, acc1[1][1]);
            }

#pragma unroll
            for (int nt = 0; nt < 2; ++nt)
#pragma unroll
                for (int mt = 0; mt < 2; ++mt) {
                    f32x4 g = gelu4(acc1[nt][mt] + b1q[nt]);
                    bf16x4 hq;
#pragma unroll
                    for (int rr = 0; rr < 4; ++rr) hq[rr] = (__bf16)g[rr];
                    *(bf16x4*)&sm.sHm[mt * 16 + lc][w * 32 + nt * 16 + lg * 4] = hq;
                }
            BAR();  // bar2: sHm ready

            f32x4 acc2[2];
            acc2[0] = (f32x4){0.f, 0.f, 0.f, 0.f};
            acc2[1] = (f32x4){0.f, 0.f, 0.f, 0.f};
#pragma unroll
            for (int kt = 0; kt < 4; ++kt) {
                bf16x8 h0 = *(const bf16x8*)&sm.sHm[lc][kt * 32 + lg * 8];
                bf16x8 h1 = *(const bf16x8*)&sm.sHm[16 + lc][kt * 32 + lg * 8];
                acc2[0] = mfma_16x16x32(wb2[kt], h0, acc2[0]);
                acc2[1] = mfma_16x16x32(wb2[kt], h1, acc2[1]);
            }
            {
                f32x4 m0 = acc2[0] + b2q;
                f32x4 m1 = acc2[1] + b2q;
                *(f32x4*)&sm.sMsg[lc][w * 16 + lg * 4]      = m0;
                *(f32x4*)&sm.sMsg[16 + lc][w * 16 + lg * 4] = m1;
            }
            BAR();  // bar3: sMsg ready (cross-wave)

            {
                const int c  = tid & 63;
                const int r0 = (tid >> 6) * 8;
                int   curo = sm.sO2[pp][r0];
                float run  = sm.sMsg[r0][c];
#pragma unroll
                for (int k2 = 1; k2 < 8; ++k2) {
                    int   o = sm.sO2[pp][r0 + k2];
                    float v = sm.sMsg[r0 + k2][c];
                    if (o != curo) {
                        atomicAdd(&A[(size_t)curo * ES + c], run);
                        curo = o;
                        run  = v;
                    } else {
                        run += v;
                    }
                }
                atomicAdd(&A[(size_t)curo * ES + c], run);
            }
            ecur = enxt;
            enxt = efut;
            pp ^= 1;
        }
    }
}

// standalone (fallback path)
__global__ __launch_bounds__(256, 4) void k_msg(
    const int4* __restrict__ eT,
    const __bf16* __restrict__ hb, const __bf16* __restrict__ ebb,
    float* __restrict__ A,
    const __bf16* __restrict__ w1b, const float* __restrict__ b1,
    const __bf16* __restrict__ w2b, const float* __restrict__ b2) {
    __shared__ SmemT sm;
    msg_layer(sm, eT, hb, ebb, A, w1b, b1, w2b, b2);
}

// fused: msg(L0) -> grid barrier -> h2b -> grid barrier -> msg(L1)
__global__ __launch_bounds__(256, 4) void k_layers(
    const int4* __restrict__ eT, __bf16* __restrict__ hb,
    const __bf16* __restrict__ ebb, float* __restrict__ A,
    const __bf16* __restrict__ w1b, const float* __restrict__ b1,
    const __bf16* __restrict__ w2b, const float* __restrict__ b2,
    int* __restrict__ bctr) {
    __shared__ SmemT sm;
    msg_layer(sm, eT, hb, ebb, A, w1b, b1, w2b, b2);
    grid_barrier(&bctr[0]);
    // h2b inline: refresh bf16 mirror from accumulated A
    {
        const int nv4 = NV_ELEMS / 4;
        const float4* a4 = (const float4*)A;
        for (int i = blockIdx.x * 256 + threadIdx.x; i < nv4; i += MSG_GRID * 256) {
            float4 v = a4[i];
            bf16x4 p;
            p[0] = (__bf16)v.x; p[1] = (__bf16)v.y;
            p[2] = (__bf16)v.z; p[3] = (__bf16)v.w;
            *(bf16x4*)(hb + (size_t)i * 4) = p;
        }
    }
    grid_barrier(&bctr[16]);
    msg_layer(sm, eT, hb, ebb, A, w1b + 24576, b1 + 128, w2b + 8192, b2 + 64);
}

__global__ void k_pool(const float* __restrict__ h, float* __restrict__ pooled) {
    __shared__ float sm[256 * 4];
    const int nv4 = NV_ELEMS / 4;
    f32x4 acc = (f32x4){0.f, 0.f, 0.f, 0.f};
    for (int i4 = blockIdx.x * 256 + threadIdx.x; i4 < nv4; i4 += gridDim.x * 256)
        acc += *(const f32x4*)(h + (size_t)i4 * 4);
    *(f32x4*)&sm[threadIdx.x * 4] = acc;
    __syncthreads();
    if (threadIdx.x < 64) {
        const int q = threadIdx.x >> 2;
        const int j = threadIdx.x & 3;
        float s = 0.f;
#pragma unroll
        for (int m = 0; m < 16; ++m) s += sm[(m * 16 + q) * 4 + j];
        atomicAdd(&pooled[q * 4 + j], s);
    }
}

__global__ void k_final(const float* __restrict__ pooled, const float* __restrict__ w,
                        const float* __restrict__ b, float* __restrict__ out) {
    __shared__ float sp[64];
    if (threadIdx.x < 64) sp[threadIdx.x] = pooled[threadIdx.x] * (1.0f / N_NODES);
    __syncthreads();
    const int c = threadIdx.x;
    float s = b[c];
#pragma unroll
    for (int j = 0; j < 64; ++j) s += sp[j] * w[j * 256 + c];
    out[c] = s;
}

extern "C" void kernel_launch(void* const* d_in, const int* in_sizes, int n_in,
                              void* d_out, int out_size, void* d_ws, size_t ws_size,
                              hipStream_t stream) {
    const int*   subj = (const int*)d_in[0];
    const int*   pred = (const int*)d_in[1];
    const int*   obj  = (const int*)d_in[2];
    const float* sym  = (const float*)d_in[3];
    const float* eemb = (const float*)d_in[4];
    const float* w1   = (const float*)d_in[5];
    const float* b1   = (const float*)d_in[6];
    const float* w2   = (const float*)d_in[7];
    const float* b2   = (const float*)d_in[8];
    const float* lw   = (const float*)d_in[9];
    const float* lb   = (const float*)d_in[10];
    float* out = (float*)d_out;

    // ---- ws layout (~73 MB, all blocks 16B-aligned) ----
    char* p = (char*)d_ws;
    float*  A      = (float*)p;   p += (size_t)NV_ELEMS * 4;        // 25.6 MB
    __bf16* hb     = (__bf16*)p;  p += (size_t)NV_ELEMS * 2;        // 12.8 MB
    __bf16* ebb    = (__bf16*)p;  p += (size_t)EV_ELEMS * 2;        // 16.8 MB
    __bf16* w1b    = (__bf16*)p;  p += (size_t)2 * 24576 * 2;       // 98 KB
    __bf16* w2b    = (__bf16*)p;  p += (size_t)2 * 8192 * 2;        // 32 KB
    float*  pooled = (float*)p;   p += 256;
    int*    cnt    = (int*)p;     p += (size_t)N_NODES * 4;
    int*    bctr   = (int*)p;     p += 128;                         // 2 barrier ctrs
    int*    off    = (int*)p;     p += (size_t)(N_NODES + 4) * 4;
    int*    cur    = (int*)p;     p += (size_t)N_NODES * 4;
    int4*   eT     = (int4*)p;    p += (size_t)N_EDGES * 16;        // 16 MB
    int*    bsum   = (int*)p;     p += 400;
    (void)ws_size;

    // residency gate for the fused kernel (pure host query, capture-safe)
    int maxb = 0;
    hipError_t qerr = hipOccupancyMaxActiveBlocksPerMultiprocessor(&maxb, k_layers,
                                                                   256, 0);
    const bool fused = (qerr == hipSuccess && maxb >= 4);

    // cnt = 0 and bctr = 0 (stream-ordered, before k_init's histogram atomics)
    hipMemsetAsync(cnt, 0, (size_t)N_NODES * 4 + 128, stream);
    k_init<<<2048, 256, 0, stream>>>(sym, eemb, w1, w2, obj, A, hb, ebb, w1b, w2b,
                                     pooled, cnt);
    k_scanA<<<SCAN_NB, SCAN_B, 0, stream>>>(cnt, off, bsum);
    k_scanC<<<SCAN_NB, SCAN_B, 0, stream>>>(off, bsum, cur);
    k_fill<<<(N_EDGES / 4 + 255) / 256, 256, 0, stream>>>(subj, pred, obj, cur, eT);

    if (fused) {
        // L0 + h2b + L1 in one resident-grid kernel (2 grid barriers, 0 drains)
        k_layers<<<MSG_GRID, 256, 0, stream>>>(eT, hb, ebb, A, w1b, b1, w2b, b2,
                                               bctr);
    } else {
        k_msg<<<MSG_GRID, 256, 0, stream>>>(eT, hb, ebb, A, w1b, b1, w2b, b2);
        k_h2b<<<2048, 256, 0, stream>>>(A, hb);
        k_msg<<<MSG_GRID, 256, 0, stream>>>(eT, hb, ebb, A, w1b + 24576, b1 + 128,
                                            w2b + 8192, b2 + 64);
    }
    // pool + head (v12 proven pair)
    k_pool<<<256, 256, 0, stream>>>(A, pooled);
    k_final<<<1, 256, 0, stream>>>(pooled, lw, lb, out);
}

// Round 16
// 349.482 us; speedup vs baseline: 1.5862x; 1.5862x over previous
//
#include <hip/hip_runtime.h>
#include <hip/hip_bf16.h>

// SymbolicGNN, CSR two-phase, v16 = v12 verbatim (proven best: 354.6us).
// v15 post-mortem: grid-barrier fusion of L0+h2b+L1 regressed 13x on LDS bank
// conflicts (SmemT&-passed shared memory defeated static LDS addressing) plus
// grid-barrier straggler equalization -> k_layers 910us. Fourth failed structural
// gamble vs v12 (v9 reduce-remap, v13 deferred reduce, v14 pool fusion, v15 grid
// fusion). Reverting to the proven fixed point: k_msg {3 barriers, single sMsg,
// wave-uniform reduce, gather prefetch after bar1, 2-ahead index pipeline, pinned
// weight frags, grid 1024 == residency, XCD-chunked contiguous tiles}.

#define N_NODES 100000
#define NV_ELEMS (N_NODES * 64)
#define N_EDGES 1000000
#define EV_ELEMS (131075 * 64)   // VOCAB * ES
#define ES 64
#define TILE 32
#define NTILES (N_EDGES / TILE)
#define MSG_GRID 1024            // == residency capacity: 4 blocks/CU x 256 CU
#define SCAN_B 1024
#define SCAN_NB ((N_NODES + SCAN_B - 1) / SCAN_B)   // 98

typedef __bf16 bf16x8 __attribute__((ext_vector_type(8)));
typedef __bf16 bf16x4 __attribute__((ext_vector_type(4)));
typedef float f32x4 __attribute__((ext_vector_type(4)));

__device__ __forceinline__ f32x4 mfma_16x16x32(bf16x8 a, bf16x8 b, f32x4 c) {
    return __builtin_amdgcn_mfma_f32_16x16x32_bf16(a, b, c, 0, 0, 0);
}

// LDS-only barrier: cross-thread deps in k_msg are all LDS; global loads
// (gather prefetch) and atomics stay in flight across it.
#define BAR() asm volatile("s_waitcnt lgkmcnt(0)\n\ts_barrier" ::: "memory")

// tanh-GELU via sigmoid identity: v * rcp(1 + exp2(-(2.30227911 v + 0.10294538 v^3))).
// Overflow-safe both directions. 2 transcendental + ~5 ALU per element.
__device__ __forceinline__ f32x4 gelu4(f32x4 v) {
    f32x4 z = v * (v * v * -0.10294538f + -2.30227911f);
    f32x4 t;
#pragma unroll
    for (int i = 0; i < 4; ++i) t[i] = __builtin_amdgcn_exp2f(z[i]);
    f32x4 o = t + 1.0f;
    f32x4 r;
#pragma unroll
    for (int i = 0; i < 4; ++i) r[i] = __builtin_amdgcn_rcpf(o[i]);
    return v * r;
}

__global__ void k_init(const float* __restrict__ sym, const float* __restrict__ eemb,
                       const float* __restrict__ w1, const float* __restrict__ w2,
                       const int* __restrict__ obj,
                       float* __restrict__ A, __bf16* __restrict__ hb,
                       __bf16* __restrict__ ebb,
                       __bf16* __restrict__ w1b, __bf16* __restrict__ w2b,
                       float* __restrict__ pooled, int* __restrict__ cnt) {
    const int gid = blockIdx.x * blockDim.x + threadIdx.x;
    const int gstride = gridDim.x * blockDim.x;
    const int nv4 = NV_ELEMS / 4;
    const float4* s4 = (const float4*)sym;
    float4* a4 = (float4*)A;
    for (int i = gid; i < nv4; i += gstride) {
        float4 v = s4[i];
        a4[i] = v;
        bf16x4 p;
        p[0] = (__bf16)v.x; p[1] = (__bf16)v.y; p[2] = (__bf16)v.z; p[3] = (__bf16)v.w;
        *(bf16x4*)(hb + (size_t)i * 4) = p;
    }
    const int ev4 = EV_ELEMS / 4;
    const float4* e4 = (const float4*)eemb;
    for (int i = gid; i < ev4; i += gstride) {
        float4 v = e4[i];
        bf16x4 p;
        p[0] = (__bf16)v.x; p[1] = (__bf16)v.y; p[2] = (__bf16)v.z; p[3] = (__bf16)v.w;
        *(bf16x4*)(ebb + (size_t)i * 4) = p;
    }
    // W1 -> fragment order: [layer][kt(6)][lg(4)][col(128)][i(8)], elem k = kt*32+lg*8+i
    for (int d = gid; d < 2 * 24576; d += gstride) {
        int layer = d / 24576, r = d - layer * 24576;
        int kt = r >> 12, lg = (r >> 10) & 3, col = (r >> 3) & 127, i = r & 7;
        w1b[d] = (__bf16)w1[layer * 24576 + (kt * 32 + lg * 8 + i) * 128 + col];
    }
    // W2 -> [layer][kt(4)][lg(4)][col(64)][i(8)]
    for (int d = gid; d < 2 * 8192; d += gstride) {
        int layer = d >> 13, r = d & 8191;
        int kt = r >> 11, lg = (r >> 9) & 3, col = (r >> 3) & 63, i = r & 7;
        w2b[d] = (__bf16)w2[layer * 8192 + (kt * 32 + lg * 8 + i) * 64 + col];
    }
    // histogram of obj (cnt pre-zeroed by hipMemsetAsync before this launch)
    for (int i = gid; i < N_EDGES; i += gstride) atomicAdd(&cnt[obj[i]], 1);
    if (gid < ES) pooled[gid] = 0.0f;
}

__global__ void k_h2b(const float* __restrict__ A, __bf16* __restrict__ hb) {
    const int nv4 = NV_ELEMS / 4;
    const float4* a4 = (const float4*)A;
    for (int i = blockIdx.x * blockDim.x + threadIdx.x; i < nv4;
         i += gridDim.x * blockDim.x) {
        float4 v = a4[i];
        bf16x4 p;
        p[0] = (__bf16)v.x; p[1] = (__bf16)v.y; p[2] = (__bf16)v.z; p[3] = (__bf16)v.w;
        *(bf16x4*)(hb + (size_t)i * 4) = p;
    }
}

__global__ __launch_bounds__(1024) void k_scanA(const int* __restrict__ cnt,
                                                int* __restrict__ off,
                                                int* __restrict__ bsum) {
    __shared__ int sp[SCAN_B];
    const int t = threadIdx.x;
    const int g = blockIdx.x * SCAN_B + t;
    int v = (g < N_NODES) ? cnt[g] : 0;
    sp[t] = v;
    __syncthreads();
#pragma unroll
    for (int d = 1; d < SCAN_B; d <<= 1) {
        int x = (t >= d) ? sp[t - d] : 0;
        __syncthreads();
        sp[t] += x;
        __syncthreads();
    }
    if (g < N_NODES) off[g] = sp[t] - v;
    if (t == SCAN_B - 1) bsum[blockIdx.x] = sp[t];
}

// fused B+C: each block derives its own prefix of bsum (<=97 independent L2 loads,
// pipelined), then applies it.
__global__ __launch_bounds__(1024) void k_scanC(int* __restrict__ off,
                                                const int* __restrict__ bsum,
                                                int* __restrict__ cur) {
    __shared__ int sboff;
    if (threadIdx.x == 0) {
        int run = 0;
        for (int b = 0; b < (int)blockIdx.x; ++b) run += bsum[b];
        sboff = run;
    }
    __syncthreads();
    const int g = blockIdx.x * SCAN_B + threadIdx.x;
    if (g < N_NODES) {
        int o = off[g] + sboff;
        off[g] = o;
        cur[g] = o;
    }
    if (g == 0) off[N_NODES] = N_EDGES;
}

// 4 edges/thread: 3 int4 index loads instead of 12 scalar loads
__global__ void k_fill(const int* __restrict__ subj, const int* __restrict__ pred,
                       const int* __restrict__ obj, int* __restrict__ cur,
                       int4* __restrict__ eT) {
    int e0 = (blockIdx.x * blockDim.x + threadIdx.x) * 4;
    if (e0 >= N_EDGES) return;   // N_EDGES % 4 == 0 -> full int4 in-bounds
    int4 s4 = *(const int4*)(subj + e0);
    int4 p4 = *(const int4*)(pred + e0);
    int4 o4 = *(const int4*)(obj + e0);
    int pos;
    pos = atomicAdd(&cur[o4.x], 1); eT[pos] = make_int4(s4.x, p4.x, o4.x, 0);
    pos = atomicAdd(&cur[o4.y], 1); eT[pos] = make_int4(s4.y, p4.y, o4.y, 0);
    pos = atomicAdd(&cur[o4.z], 1); eT[pos] = make_int4(s4.z, p4.z, o4.z, 0);
    pos = atomicAdd(&cur[o4.w], 1); eT[pos] = make_int4(s4.w, p4.w, o4.w, 0);
}

// ---------------- fused: edge MLP + in-tile segment reduce + atomic scatter ----------------
__global__ __launch_bounds__(256, 4) void k_msg(
    const int4* __restrict__ eT,
    const __bf16* __restrict__ hb, const __bf16* __restrict__ ebb,
    float* __restrict__ A,
    const __bf16* __restrict__ w1b, const float* __restrict__ b1,
    const __bf16* __restrict__ w2b, const float* __restrict__ b2) {
    __shared__ __bf16 sX[TILE][200];    // 12.8 KB
    __shared__ __bf16 sHm[TILE][136];   // 8.7 KB
    __shared__ float  sMsg[TILE][68];   // 8.7 KB
    __shared__ int    sO2[2][TILE];     // double-buffered obj ids

    const int tid = threadIdx.x;
    const int w   = tid >> 6;
    const int l   = tid & 63;
    const int lg  = l >> 4;
    const int lc  = l & 15;
    // staging plan: thread owns row r (32 rows), 16B chunk c8 (8 chunks), all 3 parts
    const int r  = tid >> 3;
    const int c8 = tid & 7;

    // ---- weight fragments: one 16B load each, PINNED so compiler can't remat ----
    const __bf16* w1f = w1b + (size_t)(lg * 1024 + (w * 32 + lc) * 8);  // + kt*4096 + nt*128
    const __bf16* w2f = w2b + (size_t)(lg * 512 + (w * 16 + lc) * 8);   // + kt*2048
    bf16x8 wb1[6][2];
#pragma unroll
    for (int kt = 0; kt < 6; ++kt)
#pragma unroll
        for (int nt = 0; nt < 2; ++nt) {
            wb1[kt][nt] = *(const bf16x8*)(w1f + kt * 4096 + nt * 128);
            asm volatile("" : "+v"(wb1[kt][nt]));   // pin: force register residency
        }
    bf16x8 wb2[4];
#pragma unroll
    for (int kt = 0; kt < 4; ++kt) {
        wb2[kt] = *(const bf16x8*)(w2f + kt * 2048);
        asm volatile("" : "+v"(wb2[kt]));
    }

    f32x4 b1q[2];
    b1q[0] = *(const f32x4*)(b1 + w * 32 + lg * 4);
    b1q[1] = *(const f32x4*)(b1 + w * 32 + 16 + lg * 4);
    f32x4 b2q = *(const f32x4*)(b2 + w * 16 + lg * 4);

    // ---- XCD-chunked contiguous tile range (grid == residency capacity) ----
    const int chunk = ((blockIdx.x & 7) << 7) + (blockIdx.x >> 3);
    int       tile  = (int)(((long long)chunk * NTILES) >> 10);
    const int tend  = (int)(((long long)(chunk + 1) * NTILES) >> 10);
    if (tile >= tend) return;

    int j0 = tile * TILE;
    int pp = 0;

    // prologue: 2-ahead index pipeline + first tile's gathers
    int4 ecur = eT[j0 + r];
    const int jn1 = (tile + 1 < tend) ? (tile + 1) * TILE : j0;
    int4 enxt = eT[jn1 + r];
    bf16x8 rb0 = *(const bf16x8*)(hb  + (size_t)ecur.x * ES + c8 * 8);
    bf16x8 rb1 = *(const bf16x8*)(ebb + (size_t)ecur.y * ES + c8 * 8);
    bf16x8 rb2 = *(const bf16x8*)(hb  + (size_t)ecur.z * ES + c8 * 8);

    for (; tile < tend; ++tile) {
        const int jf = (tile + 2 < tend) ? (tile + 2) * TILE : j0;

        // ---- stage current tile (3 x ds_write_b128); issue tile+2's index load ----
        *(bf16x8*)&sX[r][      c8 * 8] = rb0;
        *(bf16x8*)&sX[r][ 64 + c8 * 8] = rb1;
        *(bf16x8*)&sX[r][128 + c8 * 8] = rb2;
        if (c8 == 0) sO2[pp][r] = ecur.z;
        int4 efut = eT[jf + r];
        BAR();  // bar1: sX, sO2 ready

        // ---- prefetch tile+1's gathers (index loaded a full iteration ago) ----
        rb0 = *(const bf16x8*)(hb  + (size_t)enxt.x * ES + c8 * 8);
        rb1 = *(const bf16x8*)(ebb + (size_t)enxt.y * ES + c8 * 8);
        rb2 = *(const bf16x8*)(hb  + (size_t)enxt.z * ES + c8 * 8);

        // ---- GEMM1 (transposed): C[outcol][edge] ----
        f32x4 acc1[2][2];
#pragma unroll
        for (int nt = 0; nt < 2; ++nt)
#pragma unroll
            for (int mt = 0; mt < 2; ++mt) acc1[nt][mt] = (f32x4){0.f, 0.f, 0.f, 0.f};
#pragma unroll
        for (int kt = 0; kt < 6; ++kt) {
            bf16x8 x0 = *(const bf16x8*)&sX[lc][kt * 32 + lg * 8];
            bf16x8 x1 = *(const bf16x8*)&sX[16 + lc][kt * 32 + lg * 8];
            acc1[0][0] = mfma_16x16x32(wb1[kt][0], x0, acc1[0][0]);
            acc1[0][1] = mfma_16x16x32(wb1[kt][0], x1, acc1[0][1]);
            acc1[1][0] = mfma_16x16x32(wb1[kt][1], x0, acc1[1][0]);
            acc1[1][1] = mfma_16x16x32(wb1[kt][1], x1, acc1[1][1]);
        }

        // ---- bias + GELU, packed b64 writes: 4 consecutive hmid cols per lane ----
#pragma unroll
        for (int nt = 0; nt < 2; ++nt)
#pragma unroll
            for (int mt = 0; mt < 2; ++mt) {
                f32x4 g = gelu4(acc1[nt][mt] + b1q[nt]);
                bf16x4 hq;
#pragma unroll
                for (int rr = 0; rr < 4; ++rr) hq[rr] = (__bf16)g[rr];
                *(bf16x4*)&sHm[mt * 16 + lc][w * 32 + nt * 16 + lg * 4] = hq;
            }
        BAR();  // bar2: sHm ready

        // ---- GEMM2 (transposed): lane holds msg[edge][4 consecutive cols] ----
        f32x4 acc2[2];
        acc2[0] = (f32x4){0.f, 0.f, 0.f, 0.f};
        acc2[1] = (f32x4){0.f, 0.f, 0.f, 0.f};
#pragma unroll
        for (int kt = 0; kt < 4; ++kt) {
            bf16x8 h0 = *(const bf16x8*)&sHm[lc][kt * 32 + lg * 8];
            bf16x8 h1 = *(const bf16x8*)&sHm[16 + lc][kt * 32 + lg * 8];
            acc2[0] = mfma_16x16x32(wb2[kt], h0, acc2[0]);
            acc2[1] = mfma_16x16x32(wb2[kt], h1, acc2[1]);
        }
        {
            f32x4 m0 = acc2[0] + b2q;
            f32x4 m1 = acc2[1] + b2q;
            *(f32x4*)&sMsg[lc][w * 16 + lg * 4]      = m0;
            *(f32x4*)&sMsg[16 + lc][w * 16 + lg * 4] = m1;
        }
        BAR();  // bar3: sMsg ready (cross-wave: reducer reads all waves' cols)

        // ---- in-tile segment reduce: wave-uniform run breaks, 256B-coalesced atomics ----
        {
            const int c  = tid & 63;           // 64 consecutive cols per wave
            const int r0 = (tid >> 6) * 8;     // one row-group per wave
            int   curo = sO2[pp][r0];
            float run  = sMsg[r0][c];
#pragma unroll
            for (int k2 = 1; k2 < 8; ++k2) {
                int   o = sO2[pp][r0 + k2];
                float v = sMsg[r0 + k2][c];
                if (o != curo) {
                    atomicAdd(&A[(size_t)curo * ES + c], run);
                    curo = o;
                    run  = v;
                } else {
                    run += v;
                }
            }
            atomicAdd(&A[(size_t)curo * ES + c], run);
        }
        ecur = enxt;
        enxt = efut;
        pp ^= 1;
    }
}

__global__ void k_pool(const float* __restrict__ h, float* __restrict__ pooled) {
    __shared__ float sm[256 * 4];
    const int nv4 = NV_ELEMS / 4;
    f32x4 acc = (f32x4){0.f, 0.f, 0.f, 0.f};
    for (int i4 = blockIdx.x * 256 + threadIdx.x; i4 < nv4; i4 += gridDim.x * 256)
        acc += *(const f32x4*)(h + (size_t)i4 * 4);
    *(f32x4*)&sm[threadIdx.x * 4] = acc;
    __syncthreads();
    if (threadIdx.x < 64) {
        const int q = threadIdx.x >> 2;
        const int j = threadIdx.x & 3;
        float s = 0.f;
#pragma unroll
        for (int m = 0; m < 16; ++m) s += sm[(m * 16 + q) * 4 + j];
        atomicAdd(&pooled[q * 4 + j], s);
    }
}

__global__ void k_final(const float* __restrict__ pooled, const float* __restrict__ w,
                        const float* __restrict__ b, float* __restrict__ out) {
    __shared__ float sp[64];
    if (threadIdx.x < 64) sp[threadIdx.x] = pooled[threadIdx.x] * (1.0f / N_NODES);
    __syncthreads();
    const int c = threadIdx.x;
    float s = b[c];
#pragma unroll
    for (int j = 0; j < 64; ++j) s += sp[j] * w[j * 256 + c];
    out[c] = s;
}

extern "C" void kernel_launch(void* const* d_in, const int* in_sizes, int n_in,
                              void* d_out, int out_size, void* d_ws, size_t ws_size,
                              hipStream_t stream) {
    const int*   subj = (const int*)d_in[0];
    const int*   pred = (const int*)d_in[1];
    const int*   obj  = (const int*)d_in[2];
    const float* sym  = (const float*)d_in[3];
    const float* eemb = (const float*)d_in[4];
    const float* w1   = (const float*)d_in[5];
    const float* b1   = (const float*)d_in[6];
    const float* w2   = (const float*)d_in[7];
    const float* b2   = (const float*)d_in[8];
    const float* lw   = (const float*)d_in[9];
    const float* lb   = (const float*)d_in[10];
    float* out = (float*)d_out;

    // ---- ws layout (~73 MB, all blocks 16B-aligned) ----
    char* p = (char*)d_ws;
    float*  A      = (float*)p;   p += (size_t)NV_ELEMS * 4;        // 25.6 MB
    __bf16* hb     = (__bf16*)p;  p += (size_t)NV_ELEMS * 2;        // 12.8 MB
    __bf16* ebb    = (__bf16*)p;  p += (size_t)EV_ELEMS * 2;        // 16.8 MB
    __bf16* w1b    = (__bf16*)p;  p += (size_t)2 * 24576 * 2;       // 98 KB
    __bf16* w2b    = (__bf16*)p;  p += (size_t)2 * 8192 * 2;        // 32 KB
    float*  pooled = (float*)p;   p += 256;
    int*    cnt    = (int*)p;     p += (size_t)N_NODES * 4;
    int*    off    = (int*)p;     p += (size_t)(N_NODES + 4) * 4;
    int*    cur    = (int*)p;     p += (size_t)N_NODES * 4;
    int4*   eT     = (int4*)p;    p += (size_t)N_EDGES * 16;        // 16 MB
    int*    bsum   = (int*)p;     p += 400;
    (void)ws_size;

    // cnt = 0 (stream-ordered, completes before k_init's histogram atomics)
    hipMemsetAsync(cnt, 0, (size_t)N_NODES * 4, stream);
    k_init<<<2048, 256, 0, stream>>>(sym, eemb, w1, w2, obj, A, hb, ebb, w1b, w2b,
                                     pooled, cnt);
    k_scanA<<<SCAN_NB, SCAN_B, 0, stream>>>(cnt, off, bsum);
    k_scanC<<<SCAN_NB, SCAN_B, 0, stream>>>(off, bsum, cur);
    k_fill<<<(N_EDGES / 4 + 255) / 256, 256, 0, stream>>>(subj, pred, obj, cur, eT);
    // layer 0: gather hb, fused reduce-scatter into A (A pre-initialized to h0)
    k_msg<<<MSG_GRID, 256, 0, stream>>>(eT, hb, ebb, A, w1b, b1, w2b, b2);
    // refresh bf16 mirror
    k_h2b<<<2048, 256, 0, stream>>>(A, hb);
    // layer 1: gather hb, scatter in-place into A
    k_msg<<<MSG_GRID, 256, 0, stream>>>(eT, hb, ebb, A, w1b + 24576, b1 + 128,
                                        w2b + 8192, b2 + 64);
    // pool + head
    k_pool<<<256, 256, 0, stream>>>(A, pooled);
    k_final<<<1, 256, 0, stream>>>(pooled, lw, lb, out);
}